// Round 3
// baseline (116.503 us; speedup 1.0000x reference)
//
#include <hip/hip_runtime.h>
#include <math.h>

// Problem constants (fixed by setup_inputs)
constexpr int B = 32;
constexpr int N = 65;    // seq_len + 1
constexpr int D = 512;
constexpr int S = 64;    // N - 1
constexpr int M = B * N; // 2080 rows for the QK projection GEMM

// out0 layout: [B, S, S+1, D] = 68,157,440 floats. The b=31 block
// (last 2,129,920 floats) is EXACTLY q (M*D) + kT (B*D*N) — we stage q/kT
// there; the K4 dense bit-gated fill overwrites it at the end.
constexpr size_t OUT0_ELEMS = (size_t)B * S * (S + 1) * D;       // 68,157,440
constexpr size_t Q_ELEMS    = (size_t)M * D;                      // 1,064,960
constexpr size_t KT_ELEMS   = (size_t)B * D * N;                  // 1,064,960
constexpr size_t STAGE_BASE = OUT0_ELEMS - Q_ELEMS - KT_ELEMS;    // b31 start
constexpr int OUT0_F4 = (int)(OUT0_ELEMS / 4);                    // 17,039,360

// Zero-fill split across kernels (float4 units). F_C is row-aligned
// (row = 65*128 f4 = 8320) so scatter rows never straddle the boundary.
constexpr int F_A = 6291456;                   // K1 fills [0, F_A)       ~96 MB
constexpr int F_B = 10485760;                  // K2 fills [F_A, F_B)     ~64 MB
constexpr int ROW_F4 = (S + 1) * (D / 4);      // 8320
constexpr int ROWS_SCATTER = 1383;             // rows covered by zeros+scatter
constexpr int F_C = ROW_F4 * ROWS_SCATTER;     // 11,506,560; K3 fills [F_B, F_C)

// K1 grid
constexpr int NG_GEMM = 528;   // 33 m-tiles x 8 n-tiles x 2 matrices
constexpr int NG_FILL = 1536;
// K2 grid
constexpr int N2_ATTN = 512;   // 4 rows per block
constexpr int N2_FILL = 768;
// K3 grid
constexpr int N3_FILL = 255;
// K4 grid
constexpr int N4_DENSE = 2048;
constexpr int N4_TAIL  = 130;  // (B*S + B*S*S)/4 = 33,280 f4 = 130*256

// ---------------------------------------------------------------------------
// K1: fused projection GEMM (q = nve@Wq^T+bq row-major; kT[b][d][n]) plus
// zero-fill of out0[0, F_A). GEMM: 64x64 tile, BK=32, 256 thr, 4x4 microtile.
// ---------------------------------------------------------------------------
__global__ __launch_bounds__(256) void k1_gemm_fill(
    const float* __restrict__ nve, const float* __restrict__ Wq,
    const float* __restrict__ bq, const float* __restrict__ Wk,
    const float* __restrict__ bk, float* __restrict__ out)
{
    __shared__ float As[32][68];
    __shared__ float Ws[32][68];

    const int gid = blockIdx.x;
    const int tid = threadIdx.x;

    if (gid < NG_GEMM) {
        const int mat = gid >= (NG_GEMM / 2);
        const int t   = mat ? gid - NG_GEMM / 2 : gid;
        const int bm  = (t % 33) * 64;
        const int bn  = (t / 33) * 64;
        const float* W    = mat ? Wk : Wq;
        const float* bias = mat ? bk : bq;

        float* q  = out + STAGE_BASE;            // [M][D]
        float* kT = q + Q_ELEMS;                 // [B][D][N]

        const int tr = tid / 16;
        const int tc = tid % 16;
        float acc[4][4] = {};

        for (int k0 = 0; k0 < D; k0 += 32) {
            const int r  = tid / 8;
            const int c4 = (tid % 8) * 4;
            #pragma unroll
            for (int p = 0; p < 2; ++p) {
                const int rr = p * 32 + r;
                const int gm = bm + rr;
                float4 v = make_float4(0.f, 0.f, 0.f, 0.f);
                if (gm < M) v = *(const float4*)&nve[(size_t)gm * D + k0 + c4];
                As[c4 + 0][rr] = v.x; As[c4 + 1][rr] = v.y;
                As[c4 + 2][rr] = v.z; As[c4 + 3][rr] = v.w;
                float4 w = *(const float4*)&W[(size_t)(bn + rr) * D + k0 + c4];
                Ws[c4 + 0][rr] = w.x; Ws[c4 + 1][rr] = w.y;
                Ws[c4 + 2][rr] = w.z; Ws[c4 + 3][rr] = w.w;
            }
            __syncthreads();

            #pragma unroll
            for (int kk = 0; kk < 32; ++kk) {
                float a[4], w[4];
                #pragma unroll
                for (int u = 0; u < 4; ++u) a[u] = As[kk][tr * 4 + u];
                #pragma unroll
                for (int u = 0; u < 4; ++u) w[u] = Ws[kk][tc * 4 + u];
                #pragma unroll
                for (int i = 0; i < 4; ++i)
                    #pragma unroll
                    for (int j = 0; j < 4; ++j)
                        acc[i][j] += a[i] * w[j];
            }
            __syncthreads();
        }

        #pragma unroll
        for (int i = 0; i < 4; ++i) {
            const int gm = bm + tr * 4 + i;
            if (gm >= M) continue;
            const int b = gm / N;
            const int n = gm % N;
            if (mat == 0) {
                float4 v;
                v.x = acc[i][0] + bias[bn + tc * 4 + 0];
                v.y = acc[i][1] + bias[bn + tc * 4 + 1];
                v.z = acc[i][2] + bias[bn + tc * 4 + 2];
                v.w = acc[i][3] + bias[bn + tc * 4 + 3];
                *(float4*)&q[(size_t)gm * D + bn + tc * 4] = v;
            } else {
                #pragma unroll
                for (int j = 0; j < 4; ++j) {
                    const int gd = bn + tc * 4 + j;
                    kT[(size_t)b * D * N + (size_t)gd * N + n] = acc[i][j] + bias[gd];
                }
            }
        }
    } else {
        const float4 z = make_float4(0.f, 0.f, 0.f, 0.f);
        float4* o4 = (float4*)out;
        const int nthr = NG_FILL * 256;
        for (int f = (gid - NG_GEMM) * 256 + tid; f < F_A; f += nthr)
            o4[f] = z;
    }
}

// ---------------------------------------------------------------------------
// K2: 4 attention rows per block (waves 0..3 each own one row's softmax),
// kT read once per block. Plus zero-fill of [F_A, F_B).
// ---------------------------------------------------------------------------
__global__ __launch_bounds__(256) void k2_attn(
    const float* __restrict__ out, unsigned long long* __restrict__ mem,
    float* __restrict__ outw)
{
    const int gid = blockIdx.x;
    const int t = threadIdx.x;

    if (gid < N2_ATTN) {
        const float* q  = out + STAGE_BASE;
        const float* kT = q + Q_ELEMS;

        const int b = gid / 16;          // 16 blocks per batch
        const int rbase = (gid % 16) * 4;

        __shared__ float qrow[4][D];
        __shared__ float sc[4][N];

        // stage 4 q rows (attn rows rbase+1 .. rbase+4)
        #pragma unroll
        for (int w = 0; w < 4; ++w) {
            if (t < 128) {
                const int i = rbase + w + 1;
                *(float4*)&qrow[w][t * 4] =
                    *(const float4*)&q[((size_t)b * N + i) * D + t * 4];
            }
        }
        __syncthreads();

        if (t < N) {
            const float* kp = &kT[(size_t)b * D * N];
            float a0 = 0.f, a1 = 0.f, a2 = 0.f, a3 = 0.f;
            for (int e = 0; e < D; ++e) {
                const float kv = kp[(size_t)e * N + t];
                a0 += qrow[0][e] * kv;
                a1 += qrow[1][e] * kv;
                a2 += qrow[2][e] * kv;
                a3 += qrow[3][e] * kv;
            }
            const float c = 0.044194173824159216f;  // 1/sqrt(512)
            float s0 = a0 * c, s1 = a1 * c, s2 = a2 * c, s3 = a3 * c;
            if (t == rbase + 1) s0 = 0.f;
            if (t == rbase + 2) s1 = 0.f;
            if (t == rbase + 3) s2 = 0.f;
            if (t == rbase + 4) s3 = 0.f;
            sc[0][t] = s0; sc[1][t] = s1; sc[2][t] = s2; sc[3][t] = s3;
        }
        __syncthreads();

        {
            const int w = t >> 6;        // wave 0..3 -> row rbase+w
            const int lane = t & 63;
            const int i = rbase + w + 1;
            float mx = -INFINITY;
            for (int j = 0; j < N; ++j) mx = fmaxf(mx, sc[w][j]);
            float sum = 0.f;
            for (int j = 0; j < N; ++j) sum += expf(sc[w][j] - mx);
            const float p = expf(sc[w][lane + 1] - mx) / sum;
            const bool bit = (p > 0.05f) || (lane + 1 == i);
            unsigned long long mask = __ballot(bit);
            if (lane == 0) mem[b * S + rbase + w] = mask;
        }
    } else {
        const float4 z = make_float4(0.f, 0.f, 0.f, 0.f);
        float4* o4 = (float4*)outw;
        const int nthr = N2_FILL * 256;
        for (int f = F_A + (gid - N2_ATTN) * 256 + t; f < F_B; f += nthr)
            o4[f] = z;
    }
}

// ---------------------------------------------------------------------------
// K3: greedy sequential clustering (block 0) + zero-fill of [F_B, F_C).
// ---------------------------------------------------------------------------
__global__ __launch_bounds__(256) void k3_cluster(
    const unsigned long long* __restrict__ mem,
    unsigned long long* __restrict__ sel,
    unsigned long long* __restrict__ lead,
    float* __restrict__ out)
{
    const int gid = blockIdx.x;
    const int t = threadIdx.x;
    if (gid == 0) {
        if (t >= B) return;
        const int b = t;
        unsigned long long used = 0ull, lb = 0ull;
        for (int i = 0; i < S; ++i) {
            const unsigned long long row = mem[b * S + i];
            const bool active = !((used >> i) & 1ull);
            const unsigned long long sl = active ? row : 0ull;
            used |= sl;
            lb |= (unsigned long long)active << i;
            sel[b * S + i] = sl;
        }
        lead[b] = lb;
    } else {
        const float4 z = make_float4(0.f, 0.f, 0.f, 0.f);
        float4* o4 = (float4*)out;
        const int nthr = N3_FILL * 256;
        for (int f = F_B + (gid - 1) * 256 + t; f < F_C; f += nthr)
            o4[f] = z;
    }
}

// ---------------------------------------------------------------------------
// K4: (C) scatter nonzero rows in [0, ROWS_SCATTER) — zeros already written;
// (A) dense bit-gated fill of rows [ROWS_SCATTER, 2048) incl. staging region;
// (B) leader/member tail.
// ---------------------------------------------------------------------------
__global__ __launch_bounds__(256) void k4_finish(
    const float* __restrict__ nve, const float* __restrict__ cls,
    const unsigned long long* __restrict__ sel,
    const unsigned long long* __restrict__ lead,
    float* __restrict__ out)
{
    const int gid = blockIdx.x;
    const int t = threadIdx.x;

    if (gid < ROWS_SCATTER) {
        const int b = gid / S;
        const int i = gid % S;
        const unsigned long long lb = lead[b];
        const unsigned long long sb = sel[b * S + i];
        const int h = t >> 7;
        const int tt = t & 127;
        float4* slot0 = (float4*)(out + (((size_t)b * S + i) * (S + 1)) * D);
        for (int s = h; s <= S; s += 2) {
            bool on = (s == 0) ? ((lb >> i) & 1ull) : ((sb >> (s - 1)) & 1ull);
            if (!on) continue;
            const float* src = (s == 0) ? cls : &nve[((size_t)b * N + s) * D];
            slot0[(size_t)s * 128 + tt] = ((const float4*)src)[tt];
        }
    } else if (gid < ROWS_SCATTER + N4_DENSE) {
        float4* o4 = (float4*)out;
        const int nthr = N4_DENSE * 256;
        for (int f = F_C + (gid - ROWS_SCATTER) * 256 + t; f < OUT0_F4; f += nthr) {
            const int d4 = f & 127;
            const int slot = f >> 7;
            const int s = slot % (S + 1);
            const int row = slot / (S + 1);
            const int i = row % S;
            const int b = row / S;
            bool on;
            const float* src;
            if (s == 0) {
                on = (lead[b] >> i) & 1ull;
                src = &cls[d4 * 4];
            } else {
                on = (sel[b * S + i] >> (s - 1)) & 1ull;
                src = &nve[((size_t)b * N + s) * D + d4 * 4];
            }
            float4 v = make_float4(0.f, 0.f, 0.f, 0.f);
            if (on) v = *(const float4*)src;
            o4[f] = v;
        }
    } else {
        const int f = (gid - ROWS_SCATTER - N4_DENSE) * 256 + t;   // f4 index
        float* tail = out + OUT0_ELEMS;
        float4 v;
        #pragma unroll
        for (int c = 0; c < 4; ++c) {
            const int idx = f * 4 + c;
            float x;
            if (idx < B * S) {
                x = (float)((lead[idx / S] >> (idx % S)) & 1ull);
            } else {
                const int m = idx - B * S;
                const int b = m / (S * S);
                const int rem = m % (S * S);
                x = (float)((sel[b * S + rem / S] >> (rem % S)) & 1ull);
            }
            ((float*)&v)[c] = x;
        }
        *(float4*)&tail[(size_t)f * 4] = v;
    }
}

extern "C" void kernel_launch(void* const* d_in, const int* in_sizes, int n_in,
                              void* d_out, int out_size, void* d_ws, size_t ws_size,
                              hipStream_t stream) {
    const float* nve = (const float*)d_in[1];
    const float* Wq  = (const float*)d_in[2];
    const float* bq  = (const float*)d_in[3];
    const float* Wk  = (const float*)d_in[4];
    const float* bk  = (const float*)d_in[5];
    const float* cls = (const float*)d_in[6];

    float* out = (float*)d_out;

    unsigned long long* mem  = (unsigned long long*)d_ws;       // B*S
    unsigned long long* sel  = mem + B * S;                     // B*S
    unsigned long long* lead = sel + B * S;                     // B

    k1_gemm_fill<<<NG_GEMM + NG_FILL, 256, 0, stream>>>(nve, Wq, bq, Wk, bk, out);
    k2_attn<<<N2_ATTN + N2_FILL, 256, 0, stream>>>(out, mem, out);
    k3_cluster<<<1 + N3_FILL, 256, 0, stream>>>(mem, sel, lead, out);
    k4_finish<<<ROWS_SCATTER + N4_DENSE + N4_TAIL, 256, 0, stream>>>(nve, cls, sel, lead, out);
}